// Round 8
// baseline (282.021 us; speedup 1.0000x reference)
//
#include <hip/hip_runtime.h>
#include <math.h>

// Problem constants
#define Bsz 32
#define Nn  4096
#define DU  64
#define Dm  128

#define GRID_MLP 1024   // 1024 blocks x 4 waves = 4096 waves; 2 tiles/wave; 3 blocks/CU
#define NWAVE 4
#define WAVES_PER_BATCH 128   // 4096 waves / 32 batches

// workspace layout (float offsets)
#define WS_WKQ 0      // [2][128]  Wk-slice @ q per head
#define WS_BKQ 256    // [2]       bk-slice . q
#define WS_CNT 288    // [32] int  per-batch completion counters   <- zeroed by K0
#define WS_A   320    // [32][2]   sum of alpha                    <- zeroed by K0
#define WS_S   384    // [32][2][128] sum alpha*z                  <- zeroed by K0
#define WS_WP  8576   // packed bf16 MFMA frag streams: 48 frags * 64 lanes * 8 ushort

#define H1STR 136     // shorts per h1 LDS row (128 + 8 pad); 272B stride, 16B-aligned reads

typedef short frag_ab __attribute__((ext_vector_type(8)));
typedef float frag_cd __attribute__((ext_vector_type(4)));

__device__ __forceinline__ unsigned short f2bf(float x) {   // RNE
    union { float f; unsigned int u; } c; c.f = x;
    unsigned int r = c.u + 0x7fffu + ((c.u >> 16) & 1u);
    return (unsigned short)(r >> 16);
}

// gelu(x) = x * sigmoid(2y) (exact identity for tanh-gelu), log2e folded
__device__ __forceinline__ float gelu_fast(float x) {
    float t = x * x;
    float a = x * fmaf(t, -0.1029432f, -2.3022081f);
    float e = __builtin_amdgcn_exp2f(a);
    return x * __builtin_amdgcn_rcpf(1.0f + e);
}

// K0: 14 blocks. 0..11 pack W1/W2 into MFMA frag bf16 streams (stay L2-hot);
// 12 computes qv/wkq/bkq; 13 zeroes CNT/A/S. Packing is role-symmetric: same
// frags serve as A-operands (W1, transposed layer 1) and B-operands (W2).
__global__ __launch_bounds__(256) void precompute_kernel(
    const float* __restrict__ embed, const float* __restrict__ Wq,
    const float* __restrict__ bq, const float* __restrict__ Wk,
    const float* __restrict__ bk, const float* __restrict__ W1,
    const float* __restrict__ W2, float* __restrict__ ws)
{
    __shared__ float qv[128];
    const int tid = threadIdx.x;
    const int bid = blockIdx.x;

    if (bid < 12) {
        // frag f, lane L (q2=L>>4, n=L&15) holds W[ks*32+q2*8+j][nt*16+n], j=0..7
        const int e = bid * 256 + tid;     // 0..3071
        const int f = e >> 6, L = e & 63;
        const int q2 = L >> 4, n = L & 15;
        const float* src;
        int ks, nt;
        if (f < 16) { src = W1; ks = f >> 3;        nt = f & 7; }
        else        { src = W2; ks = (f - 16) >> 3; nt = (f - 16) & 7; }
        const int kb = ks * 32 + q2 * 8;
        const int c  = nt * 16 + n;
        unsigned int p[4];
        #pragma unroll
        for (int jj = 0; jj < 4; ++jj) {
            unsigned int lo = f2bf(src[(kb + 2 * jj)     * Dm + c]);
            unsigned int hi = f2bf(src[(kb + 2 * jj + 1) * Dm + c]);
            p[jj] = lo | (hi << 16);
        }
        ((uint4*)(ws + WS_WP))[e] = make_uint4(p[0], p[1], p[2], p[3]);
    } else if (bid == 12) {
        if (tid < 128) {
            float s = bq[tid];
            #pragma unroll 8
            for (int j = 0; j < 128; ++j) s += embed[j] * Wq[j * 128 + tid];
            qv[tid] = s;
        }
        __syncthreads();
        if (tid < 128) {
            float s0 = 0.f, s1 = 0.f;
            #pragma unroll 8
            for (int dh = 0; dh < 64; ++dh) {
                s0 += Wk[tid * 128 + dh]      * qv[dh];
                s1 += Wk[tid * 128 + 64 + dh] * qv[64 + dh];
            }
            ws[WS_WKQ + tid]       = s0;
            ws[WS_WKQ + 128 + tid] = s1;
        }
        if (tid < 2) {
            float s = 0.f;
            for (int dh = 0; dh < 64; ++dh) s += bk[tid * 64 + dh] * qv[tid * 64 + dh];
            ws[WS_BKQ + tid] = s;
        }
    } else {
        for (int idx = WS_CNT + tid; idx < WS_WP; idx += 256) ws[idx] = 0.f;
    }
}

// K1: barrier-free per-wave 16-row tiles, COARSE compile-time fences.
//   R7 proved sched_barrier(0) kills the spills (WRITE 146MB->4.5MB, VGPR 88)
//   but per-ct fencing serialized each wave into ~100 dependent micro-steps at
//   only 8 waves/CU -> 177us (VALUBusy 8% with unchanged total VALU work).
//   This round: (1) fences at PHASE granularity -- layer-1 in two 4-ct halves
//   (16 W1 frags batch-loaded from global, transient), layer-2 in two 2-ks
//   groups -- ILP restored inside each region, in-flight still bounded (~64
//   frag regs max); (2) W1 out of LDS -> 52.2KB -> 3 blocks/CU = 12 waves/CU
//   (1.5x TLP), __launch_bounds__(256,3) -> VGPR cap 170 >= demand ~150.
//   Zero runtime barriers in the loop; per-wave h1 tiles; finisher epilogue.
__global__ __launch_bounds__(256, 3) void mlp_pool_kernel(
    const float* __restrict__ u,  const float* __restrict__ b1,
    const float* __restrict__ b2, const float* __restrict__ Wv,
    const float* __restrict__ bv, const float* __restrict__ Wo,
    const float* __restrict__ bo, float* __restrict__ ws,
    float* __restrict__ out)
{
    __shared__ short lds_w2[32 * 512];          // 32 KB: W2 frags 16..47
    __shared__ float b1_lds[128];
    __shared__ float b2_lds[128];
    __shared__ float wkq_lds[256];              // [head][128]
    __shared__ short lds_h1[NWAVE * 16 * H1STR];// per-wave 16x136 bf16 tiles (17 KB)

    const int tid  = threadIdx.x;
    const int wave = tid >> 6;
    const int lane = tid & 63;
    const int q    = lane >> 4;
    const int n15  = lane & 15;

    const int g  = blockIdx.x * NWAVE + wave;   // global wave id 0..4095
    const int bb = g >> 7;                      // batch 0..31 (128 waves/batch)
    const int jt = g & 127;                     // tile slot; rows jt*16 and jt*16+2048

    // issue tile-0 u loads first: they hide under W2 staging + the barrier
    const float* ub = u + ((size_t)(bb * Nn + jt * 16 + n15)) * DU + q * 8;
    float4 f0 = *(const float4*)(ub);
    float4 f1 = *(const float4*)(ub + 4);
    float4 f2 = *(const float4*)(ub + 32);
    float4 f3 = *(const float4*)(ub + 36);

    // stage W2 frags global(L2) -> LDS (32 KB, 8 uint4/thread); consts -> LDS
    const uint4* wsrc = (const uint4*)(ws + WS_WP);
    {
        uint4* dst = (uint4*)lds_w2;
        #pragma unroll
        for (int i = 0; i < 8; ++i) dst[tid + 256 * i] = wsrc[1024 + tid + 256 * i];
        if (tid < 128) b1_lds[tid]       = b1[tid];
        else           b2_lds[tid - 128] = b2[tid - 128];
        wkq_lds[tid] = ws[WS_WKQ + tid];
    }
    const float bkq0 = ws[WS_BKQ];
    const float bkq1 = ws[WS_BKQ + 1];
    __syncthreads();                 // the ONLY block barrier (staging done)

    short* h1w = lds_h1 + wave * 16 * H1STR;    // this wave's private tile

    float s0p[8], s1p[8];
    #pragma unroll
    for (int ct = 0; ct < 8; ++ct) { s0p[ct] = 0.f; s1p[ct] = 0.f; }
    float aA0 = 0.f, aA1 = 0.f;

    #pragma unroll 1
    for (int t = 0; t < 2; ++t) {
        // u tile -> bf16 (lane (q,n15) holds u[row n15][q*8+j], j=0..7 (+32))
        frag_ab a0, a1;
        a0[0] = (short)f2bf(f0.x); a0[1] = (short)f2bf(f0.y);
        a0[2] = (short)f2bf(f0.z); a0[3] = (short)f2bf(f0.w);
        a0[4] = (short)f2bf(f1.x); a0[5] = (short)f2bf(f1.y);
        a0[6] = (short)f2bf(f1.z); a0[7] = (short)f2bf(f1.w);
        a1[0] = (short)f2bf(f2.x); a1[1] = (short)f2bf(f2.y);
        a1[2] = (short)f2bf(f2.z); a1[3] = (short)f2bf(f2.w);
        a1[4] = (short)f2bf(f3.x); a1[5] = (short)f2bf(f3.y);
        a1[6] = (short)f2bf(f3.z); a1[7] = (short)f2bf(f3.w);

        // prefetch tile 1 (in flight across tile 0's compute; no barriers)
        if (t == 0) {
            const float* un = ub + (size_t)2048 * DU;
            f0 = *(const float4*)(un);
            f1 = *(const float4*)(un + 4);
            f2 = *(const float4*)(un + 32);
            f3 = *(const float4*)(un + 36);
        }
        __builtin_amdgcn_sched_barrier(0);   // fence: u-conv region closed

        // ---- layer 1, TRANSPOSED: D = W1^T-tile(16c x 64k) . u^T(64k x 16m)
        // lane (q,n15) reg r = h1[m=n15][c=ct*16+q*4+r] -> 4 consecutive cols.
        // All 16 W1 frags batch-loaded (transient, L1/L2-hot 16KB stream);
        // two 4-ct halves, ONE fence between -> ILP inside, pressure bounded.
        {
            frag_ab wa[4], wb[4], wc[4], wd[4];
            #pragma unroll
            for (int i = 0; i < 4; ++i) {
                wa[i] = *(const frag_ab*)&wsrc[(i)      * 64 + lane];  // ks0, ct i
                wb[i] = *(const frag_ab*)&wsrc[(8 + i)  * 64 + lane];  // ks1, ct i
                wc[i] = *(const frag_ab*)&wsrc[(4 + i)  * 64 + lane];  // ks0, ct 4+i
                wd[i] = *(const frag_ab*)&wsrc[(12 + i) * 64 + lane];  // ks1, ct 4+i
            }
            #pragma unroll
            for (int i = 0; i < 4; ++i) {
                const int ct = i;
                float4 bi = *(const float4*)&b1_lds[ct * 16 + q * 4];
                frag_cd acc = (frag_cd){bi.x, bi.y, bi.z, bi.w};
                acc = __builtin_amdgcn_mfma_f32_16x16x32_bf16(wa[i], a0, acc, 0, 0, 0);
                acc = __builtin_amdgcn_mfma_f32_16x16x32_bf16(wb[i], a1, acc, 0, 0, 0);
                unsigned int lo = (unsigned int)f2bf(gelu_fast(acc[0]))
                                | ((unsigned int)f2bf(gelu_fast(acc[1])) << 16);
                unsigned int hi = (unsigned int)f2bf(gelu_fast(acc[2]))
                                | ((unsigned int)f2bf(gelu_fast(acc[3])) << 16);
                *(uint2*)&h1w[n15 * H1STR + ct * 16 + q * 4] = make_uint2(lo, hi);
            }
            __builtin_amdgcn_sched_barrier(0);   // fence: half 0 closed
            #pragma unroll
            for (int i = 0; i < 4; ++i) {
                const int ct = 4 + i;
                float4 bi = *(const float4*)&b1_lds[ct * 16 + q * 4];
                frag_cd acc = (frag_cd){bi.x, bi.y, bi.z, bi.w};
                acc = __builtin_amdgcn_mfma_f32_16x16x32_bf16(wc[i], a0, acc, 0, 0, 0);
                acc = __builtin_amdgcn_mfma_f32_16x16x32_bf16(wd[i], a1, acc, 0, 0, 0);
                unsigned int lo = (unsigned int)f2bf(gelu_fast(acc[0]))
                                | ((unsigned int)f2bf(gelu_fast(acc[1])) << 16);
                unsigned int hi = (unsigned int)f2bf(gelu_fast(acc[2]))
                                | ((unsigned int)f2bf(gelu_fast(acc[3])) << 16);
                *(uint2*)&h1w[n15 * H1STR + ct * 16 + q * 4] = make_uint2(lo, hi);
            }
            __builtin_amdgcn_sched_barrier(0);   // fence: layer 1 closed
        }

        // ---- layer 2, normal: D = h1(16m x 128k) . W2(128k x 16c-tile)
        // two 2-ks groups, fence per group (in-flight <= 2x36 regs)
        frag_cd acc2[8];
        #pragma unroll
        for (int ct = 0; ct < 8; ++ct) {
            float bc = b2_lds[ct * 16 + n15];
            acc2[ct] = (frag_cd){bc, bc, bc, bc};
        }
        #pragma unroll 1
        for (int kg = 0; kg < 2; ++kg) {
            #pragma unroll
            for (int ki = 0; ki < 2; ++ki) {
                const int ks = kg * 2 + ki;
                frag_ab af = *(const frag_ab*)&h1w[n15 * H1STR + ks * 32 + q * 8];
                #pragma unroll
                for (int ct = 0; ct < 8; ++ct) {
                    frag_ab bf = *(const frag_ab*)&lds_w2[(ks * 8 + ct) * 512 + lane * 8];
                    acc2[ct] = __builtin_amdgcn_mfma_f32_16x16x32_bf16(af, bf, acc2[ct], 0, 0, 0);
                }
            }
            __builtin_amdgcn_sched_barrier(0);   // fence: ks group closed
        }
        #pragma unroll
        for (int ct = 0; ct < 8; ++ct) {
            #pragma unroll
            for (int r = 0; r < 4; ++r)
                acc2[ct][r] = gelu_fast(acc2[ct][r]);   // z, rows q*4+r, col ct*16+n15
        }

        // ---- alpha per row (full 128-col dot): partial over my 8 cols,
        // butterfly over the 16 n15 lanes (quads hold disjoint rows -> done)
        float p0[4], p1[4];
        #pragma unroll
        for (int r = 0; r < 4; ++r) { p0[r] = 0.f; p1[r] = 0.f; }
        #pragma unroll
        for (int ct = 0; ct < 8; ++ct) {
            const int c = ct * 16 + n15;
            const float w0v = wkq_lds[c];
            const float w1v = wkq_lds[128 + c];
            #pragma unroll
            for (int r = 0; r < 4; ++r) {
                p0[r] += acc2[ct][r] * w0v;
                p1[r] += acc2[ct][r] * w1v;
            }
        }
        #pragma unroll
        for (int r = 0; r < 4; ++r) {
            #pragma unroll
            for (int d = 1; d < 16; d <<= 1) {
                p0[r] += __shfl_xor(p0[r], d);
                p1[r] += __shfl_xor(p1[r], d);
            }
        }
        #pragma unroll
        for (int r = 0; r < 4; ++r) {
            const float al0 = p0[r] + bkq0;
            const float al1 = p1[r] + bkq1;
            #pragma unroll
            for (int ct = 0; ct < 8; ++ct) {
                s0p[ct] += al0 * acc2[ct][r];
                s1p[ct] += al1 * acc2[ct][r];
            }
            aA0 += al0; aA1 += al1;
        }
        __builtin_amdgcn_sched_barrier(0);   // fence: tile t retired
    }

    // cross-quad reduce (quads hold disjoint rows), one atomic batch per wave
    #pragma unroll
    for (int ct = 0; ct < 8; ++ct) {
        s0p[ct] += __shfl_xor(s0p[ct], 16); s0p[ct] += __shfl_xor(s0p[ct], 32);
        s1p[ct] += __shfl_xor(s1p[ct], 16); s1p[ct] += __shfl_xor(s1p[ct], 32);
    }
    aA0 += __shfl_xor(aA0, 16); aA0 += __shfl_xor(aA0, 32);
    aA1 += __shfl_xor(aA1, 16); aA1 += __shfl_xor(aA1, 32);

    if (q == 0) {
        #pragma unroll
        for (int ct = 0; ct < 8; ++ct) {
            const int c = ct * 16 + n15;
            atomicAdd(&ws[WS_S + (bb * 2 + 0) * 128 + c], s0p[ct]);
            atomicAdd(&ws[WS_S + (bb * 2 + 1) * 128 + c], s1p[ct]);
        }
    }
    if (lane == 0) {
        atomicAdd(&ws[WS_A + bb * 2 + 0], aA0);
        atomicAdd(&ws[WS_A + bb * 2 + 1], aA1);
    }

    // ---- per-batch completion: 128th finisher WAVE runs the epilogue alone
    __threadfence();                       // drain this wave's atomics
    int old = 0;
    if (lane == 0) old = atomicAdd((int*)ws + WS_CNT + bb, 1);
    old = __shfl(old, 0);
    if (old == WAVES_PER_BATCH - 1) {
        __threadfence();
        float* sc = (float*)h1w;           // own tile as scratch: 1088 floats
        // gather S (device-scope reads) and A
        #pragma unroll
        for (int k = 0; k < 4; ++k)
            sc[lane + 64 * k] = atomicAdd(&ws[WS_S + bb * 256 + lane + 64 * k], 0.f);
        if (lane < 2) sc[256 + lane] = atomicAdd(&ws[WS_A + bb * 2 + lane], 0.f);

        const int c0 = lane, c1 = lane + 64;       // head 0 / head 1 columns
        const float sa0 = sc[256], sa1 = sc[257];
        float d0 = sa0 * bv[c0], d1 = sa1 * bv[c1];
        #pragma unroll 8
        for (int d = 0; d < 128; ++d) {
            d0 += sc[d]       * Wv[d * 128 + c0];
            d1 += sc[128 + d] * Wv[d * 128 + c1];
        }
        sc[272 + c0] = d0 * (1.0f / 4096.0f);      // pooled
        sc[272 + c1] = d1 * (1.0f / 4096.0f);

        float o0 = bo[c0], o1 = bo[c1];
        #pragma unroll 8
        for (int d = 0; d < 128; ++d) {
            const float pd = sc[272 + d];
            o0 += pd * Wo[d * 128 + c0];
            o1 += pd * Wo[d * 128 + c1];
        }
        out[bb * 128 + c0] = o0;
        out[bb * 128 + c1] = o1;
    }
}

extern "C" void kernel_launch(void* const* d_in, const int* in_sizes, int n_in,
                              void* d_out, int out_size, void* d_ws, size_t ws_size,
                              hipStream_t stream) {
    const float* u     = (const float*)d_in[0];
    // d_in[1] = x : unused by the reference
    const float* W1    = (const float*)d_in[2];
    const float* b1    = (const float*)d_in[3];
    const float* W2    = (const float*)d_in[4];
    const float* b2    = (const float*)d_in[5];
    const float* embed = (const float*)d_in[6];
    const float* Wq    = (const float*)d_in[7];
    const float* bq    = (const float*)d_in[8];
    const float* Wk    = (const float*)d_in[9];
    const float* bk    = (const float*)d_in[10];
    const float* Wv    = (const float*)d_in[11];
    const float* bv    = (const float*)d_in[12];
    const float* Wo    = (const float*)d_in[13];
    const float* bo    = (const float*)d_in[14];
    float* ws  = (float*)d_ws;
    float* out = (float*)d_out;

    hipLaunchKernelGGL(precompute_kernel, dim3(14), dim3(256), 0, stream,
                       embed, Wq, bq, Wk, bk, W1, W2, ws);
    hipLaunchKernelGGL(mlp_pool_kernel, dim3(GRID_MLP), dim3(256), 0, stream,
                       u, b1, b2, Wv, bv, Wo, bo, ws, out);
}

// Round 9
// 150.046 us; speedup vs baseline: 1.8796x; 1.8796x over previous
//
#include <hip/hip_runtime.h>
#include <math.h>

// Problem constants
#define Bsz 32
#define Nn  4096
#define DU  64
#define Dm  128

#define GRID_MLP 512    // 2 blocks/CU (68.6 KB LDS each); 8 waves = 4 pair-tiles per block
#define BPB 16          // blocks per batch (512/32); 256 rows per block = 4 iters x 64 rows

// workspace layout (float offsets)
#define WS_WKQ 0      // [2][128]  Wk-slice @ q per head
#define WS_BKQ 256    // [2]       bk-slice . q
#define WS_CNT 288    // [32] int  per-batch completion counters   <- zeroed by K0
#define WS_A   320    // [32][2]   sum of alpha                    <- zeroed by K0
#define WS_S   384    // [32][2][128] sum alpha*z                  <- zeroed by K0
#define WS_WP  8576   // packed bf16 MFMA frag streams: 48 frags * 64 lanes * 8 ushort

#define H1STR 136     // shorts per h1 LDS row (128 + 8 pad), 16B-aligned

typedef short frag_ab __attribute__((ext_vector_type(8)));
typedef float frag_cd __attribute__((ext_vector_type(4)));

__device__ __forceinline__ unsigned short f2bf(float x) {   // RNE
    union { float f; unsigned int u; } c; c.f = x;
    unsigned int r = c.u + 0x7fffu + ((c.u >> 16) & 1u);
    return (unsigned short)(r >> 16);
}

// gelu(x) = x * sigmoid(2y) (exact identity for tanh-gelu), log2e folded
__device__ __forceinline__ float gelu_fast(float x) {
    float t = x * x;
    float a = x * fmaf(t, -0.1029432f, -2.3022081f);
    float e = __builtin_amdgcn_exp2f(a);
    return x * __builtin_amdgcn_rcpf(1.0f + e);
}

// K0: 14 blocks. 0..11 pack W1/W2 into MFMA frag bf16 streams (stay L2-hot);
// 12 computes qv/wkq/bkq; 13 zeroes CNT/A/S. Packing is role-symmetric: same
// frags serve as A-operands (W1, transposed layer 1) and B-operands (W2).
__global__ __launch_bounds__(256) void precompute_kernel(
    const float* __restrict__ embed, const float* __restrict__ Wq,
    const float* __restrict__ bq, const float* __restrict__ Wk,
    const float* __restrict__ bk, const float* __restrict__ W1,
    const float* __restrict__ W2, float* __restrict__ ws)
{
    __shared__ float qv[128];
    const int tid = threadIdx.x;
    const int bid = blockIdx.x;

    if (bid < 12) {
        // frag f, lane L (q2=L>>4, n=L&15) holds W[ks*32+q2*8+j][nt*16+n], j=0..7
        const int e = bid * 256 + tid;     // 0..3071
        const int f = e >> 6, L = e & 63;
        const int q2 = L >> 4, n = L & 15;
        const float* src;
        int ks, nt;
        if (f < 16) { src = W1; ks = f >> 3;        nt = f & 7; }
        else        { src = W2; ks = (f - 16) >> 3; nt = (f - 16) & 7; }
        const int kb = ks * 32 + q2 * 8;
        const int c  = nt * 16 + n;
        unsigned int p[4];
        #pragma unroll
        for (int jj = 0; jj < 4; ++jj) {
            unsigned int lo = f2bf(src[(kb + 2 * jj)     * Dm + c]);
            unsigned int hi = f2bf(src[(kb + 2 * jj + 1) * Dm + c]);
            p[jj] = lo | (hi << 16);
        }
        ((uint4*)(ws + WS_WP))[e] = make_uint4(p[0], p[1], p[2], p[3]);
    } else if (bid == 12) {
        if (tid < 128) {
            float s = bq[tid];
            #pragma unroll 8
            for (int j = 0; j < 128; ++j) s += embed[j] * Wq[j * 128 + tid];
            qv[tid] = s;
        }
        __syncthreads();
        if (tid < 128) {
            float s0 = 0.f, s1 = 0.f;
            #pragma unroll 8
            for (int dh = 0; dh < 64; ++dh) {
                s0 += Wk[tid * 128 + dh]      * qv[dh];
                s1 += Wk[tid * 128 + 64 + dh] * qv[64 + dh];
            }
            ws[WS_WKQ + tid]       = s0;
            ws[WS_WKQ + 128 + tid] = s1;
        }
        if (tid < 2) {
            float s = 0.f;
            for (int dh = 0; dh < 64; ++dh) s += bk[tid * 64 + dh] * qv[tid * 64 + dh];
            ws[WS_BKQ + tid] = s;
        }
    } else {
        for (int idx = WS_CNT + tid; idx < WS_WP; idx += 256) ws[idx] = 0.f;
    }
}

// K1: the 53.7us harness-verified barriered skeleton (R0) + session-verified
// upgrades. Barrier-free variants (R2-R8) all lost: no fences -> scheduler
// hoists everything -> 118-220MB spills; fences -> serial region chains,
// unhidden at low occupancy (R8: 193us, VALUBusy 7%). R0's 2 barriers/iter
// do double duty: bound scheduler pressure per phase (52 VGPR, no scratch)
// AND permit full batch-issue ILP inside each phase. Grafts onto R0:
//   1. TRANSPOSED layer-1 (mfma(W1frag, ufrag); math verified R2-R8): bias
//      folded into acc init; h1 written as 4 packed ds_write_b64 per wave/iter
//      (was 16 scalar u16 + 16 VALU bias adds).
//   2. b2 folded into acc2 init (-16 VALU/iter).
//   3. u-prefetch issued AFTER B1: drains at B2 behind ~1000cy of layer2+alpha
//      (R0 issued before B1 -> exposed at B1's vmcnt(0) drain).
// Everything else identical to R0: weights in LDS, 512-thr blocks, pair-split
// N-halves, a2buf alpha exchange, finisher-wave epilogue. NO launch_bounds
// min-arg (R3/R6 of prior session: force-caps VGPR -> spills).
__global__ __launch_bounds__(512) void mlp_pool_kernel(
    const float* __restrict__ u,  const float* __restrict__ b1,
    const float* __restrict__ b2, const float* __restrict__ Wv,
    const float* __restrict__ bv, const float* __restrict__ Wo,
    const float* __restrict__ bo, float* __restrict__ ws,
    float* __restrict__ out)
{
    __shared__ short lds_w[48 * 512];          // 48 KB weight fragments (both layers)
    __shared__ short lds_h1[4 * 16 * H1STR];   // 4 pair tiles x 16 x 136 bf16 (17.4 KB)
    __shared__ float a2buf[4][16][2][2];       // [pair][row][head][half] (1 KB)
    __shared__ float b1_lds[128];
    __shared__ int   do_epi;

    const int tid  = threadIdx.x;
    const int wave = tid >> 6;
    const int lane = tid & 63;
    const int quad = lane >> 4;
    const int n15  = lane & 15;
    const int p    = wave >> 1;     // tile pair 0..3
    const int hf   = wave & 1;      // column half

    // stage all weight fragments global(L2) -> LDS (48 KB, 6 float4/thread)
    {
        const float4* src = (const float4*)(ws + WS_WP);
        float4* dst = (float4*)lds_w;
        #pragma unroll
        for (int i = 0; i < 6; ++i) dst[tid + 512 * i] = src[tid + 512 * i];
        if (tid < 128) b1_lds[tid] = b1[tid];
    }

    // per-lane constants for this wave's column half (layer-2 C layout)
    float b2c[4], wkq0[4], wkq1[4];
    #pragma unroll
    for (int nt = 0; nt < 4; ++nt) {
        const int c = hf * 64 + nt * 16 + n15;
        b2c[nt]  = b2[c];
        wkq0[nt] = ws[WS_WKQ + c];
        wkq1[nt] = ws[WS_WKQ + 128 + c];
    }
    const float bkq0 = ws[WS_BKQ];
    const float bkq1 = ws[WS_BKQ + 1];
    __syncthreads();

    const int bb = blockIdx.x >> 4;          // batch
    const int jb = blockIdx.x & 15;          // 256-row chunk within batch
    short* h1t = lds_h1 + p * 16 * H1STR;    // pair-shared tile

    float s0p[4], s1p[4];
    #pragma unroll
    for (int nt = 0; nt < 4; ++nt) { s0p[nt] = 0.f; s1p[nt] = 0.f; }
    float aA0 = 0.f, aA1 = 0.f;

    // iter-0 u loads: lane (quad,n15) = row n15 of pair tile, k quad*8..+8, +32
    const float* ub = u + ((size_t)(bb * Nn + jb * 256 + p * 16 + n15)) * DU + quad * 8;
    float4 f0 = *(const float4*)(ub);
    float4 f1 = *(const float4*)(ub + 4);
    float4 f2 = *(const float4*)(ub + 32);
    float4 f3 = *(const float4*)(ub + 36);

    #pragma unroll 1            // keep rolled (full unroll spilled previously)
    for (int it = 0; it < 4; ++it) {
        frag_ab a0, a1;
        a0[0] = (short)f2bf(f0.x); a0[1] = (short)f2bf(f0.y);
        a0[2] = (short)f2bf(f0.z); a0[3] = (short)f2bf(f0.w);
        a0[4] = (short)f2bf(f1.x); a0[5] = (short)f2bf(f1.y);
        a0[6] = (short)f2bf(f1.z); a0[7] = (short)f2bf(f1.w);
        a1[0] = (short)f2bf(f2.x); a1[1] = (short)f2bf(f2.y);
        a1[2] = (short)f2bf(f2.z); a1[3] = (short)f2bf(f2.w);
        a1[4] = (short)f2bf(f3.x); a1[5] = (short)f2bf(f3.y);
        a1[6] = (short)f2bf(f3.z); a1[7] = (short)f2bf(f3.w);

        // ---- layer 1, TRANSPOSED: D = W1^T-tile(16c x 64k) . u^T(64k x 16m)
        // this wave's 4 ct-blocks = its column half; lane (quad,n15) reg r =
        // h1[m=n15][c=ct*16+quad*4+r] -> 4 consecutive cols, one b64 write.
        #pragma unroll
        for (int i = 0; i < 4; ++i) {
            const int ct = hf * 4 + i;
            float4 bi = *(const float4*)&b1_lds[ct * 16 + quad * 4];
            frag_cd acc = (frag_cd){bi.x, bi.y, bi.z, bi.w};       // bias folded
            frag_ab w0 = *(const frag_ab*)&lds_w[(ct)     * 512 + lane * 8];  // ks=0
            acc = __builtin_amdgcn_mfma_f32_16x16x32_bf16(w0, a0, acc, 0, 0, 0);
            frag_ab w1 = *(const frag_ab*)&lds_w[(8 + ct) * 512 + lane * 8];  // ks=1
            acc = __builtin_amdgcn_mfma_f32_16x16x32_bf16(w1, a1, acc, 0, 0, 0);
            unsigned int lo = (unsigned int)f2bf(gelu_fast(acc[0]))
                            | ((unsigned int)f2bf(gelu_fast(acc[1])) << 16);
            unsigned int hi = (unsigned int)f2bf(gelu_fast(acc[2]))
                            | ((unsigned int)f2bf(gelu_fast(acc[3])) << 16);
            *(uint2*)&h1t[n15 * H1STR + ct * 16 + quad * 4] = make_uint2(lo, hi);
        }
        __syncthreads();    // B1: both halves' h1 visible (8-wave domain)

        // prefetch next iter's u AFTER B1: drains at B2 behind layer2+alpha
        if (it < 3) {
            const float* un = ub + (size_t)((it + 1) * 64) * DU;
            f0 = *(const float4*)(un);
            f1 = *(const float4*)(un + 4);
            f2 = *(const float4*)(un + 32);
            f3 = *(const float4*)(un + 36);
        }

        // ---- layer 2 (this half's 64 cols): M16 N64 K128, B from LDS
        frag_cd acc2[4];
        #pragma unroll
        for (int nt = 0; nt < 4; ++nt)
            acc2[nt] = (frag_cd){b2c[nt], b2c[nt], b2c[nt], b2c[nt]};  // bias folded
        #pragma unroll
        for (int ks = 0; ks < 4; ++ks) {
            frag_ab a2 = *(const frag_ab*)&h1t[n15 * H1STR + ks * 32 + quad * 8];
            #pragma unroll
            for (int nt = 0; nt < 4; ++nt) {
                frag_ab w2f = *(const frag_ab*)&lds_w[(16 + ks * 8 + hf * 4 + nt) * 512 + lane * 8];
                acc2[nt] = __builtin_amdgcn_mfma_f32_16x16x32_bf16(a2, w2f, acc2[nt], 0, 0, 0);
            }
        }

        // gelu -> z (this half) fp32 in registers
        #pragma unroll
        for (int nt = 0; nt < 4; ++nt) {
            #pragma unroll
            for (int r = 0; r < 4; ++r)
                acc2[nt][r] = gelu_fast(acc2[nt][r]);
        }

        // ---- half-alpha dots, reduce over n15 lanes, publish to a2buf
        float p0[4], p1[4];
        #pragma unroll
        for (int r = 0; r < 4; ++r) { p0[r] = 0.f; p1[r] = 0.f; }
        #pragma unroll
        for (int nt = 0; nt < 4; ++nt) {
            #pragma unroll
            for (int r = 0; r < 4; ++r) {
                p0[r] += acc2[nt][r] * wkq0[nt];
                p1[r] += acc2[nt][r] * wkq1[nt];
            }
        }
        #pragma unroll
        for (int r = 0; r < 4; ++r) {
            #pragma unroll
            for (int d = 1; d < 16; d <<= 1) {
                p0[r] += __shfl_xor(p0[r], d);
                p1[r] += __shfl_xor(p1[r], d);
            }
        }
        if (n15 == 0) {
            #pragma unroll
            for (int r = 0; r < 4; ++r) {
                const int row = quad * 4 + r;
                a2buf[p][row][0][hf] = p0[r];
                a2buf[p][row][1][hf] = p1[r];
            }
        }
        __syncthreads();    // B2: alpha halves visible (also protects h1/a2buf reuse)

        // ---- full alpha for my rows; accumulate S (my cols, z in acc2) and A
        #pragma unroll
        for (int r = 0; r < 4; ++r) {
            const int row = quad * 4 + r;
            const float al0 = a2buf[p][row][0][0] + a2buf[p][row][0][1] + bkq0;
            const float al1 = a2buf[p][row][1][0] + a2buf[p][row][1][1] + bkq1;
            #pragma unroll
            for (int nt = 0; nt < 4; ++nt) {
                s0p[nt] += al0 * acc2[nt][r];
                s1p[nt] += al1 * acc2[nt][r];
            }
            aA0 += al0; aA1 += al1;
        }
    }

    // cross-quad reduce (quads hold disjoint rows), one atomic batch per wave
    #pragma unroll
    for (int nt = 0; nt < 4; ++nt) {
        s0p[nt] += __shfl_xor(s0p[nt], 16); s0p[nt] += __shfl_xor(s0p[nt], 32);
        s1p[nt] += __shfl_xor(s1p[nt], 16); s1p[nt] += __shfl_xor(s1p[nt], 32);
    }
    aA0 += __shfl_xor(aA0, 16); aA0 += __shfl_xor(aA0, 32);
    aA1 += __shfl_xor(aA1, 16); aA1 += __shfl_xor(aA1, 32);

    if (quad == 0) {
        #pragma unroll
        for (int nt = 0; nt < 4; ++nt) {
            const int c = hf * 64 + nt * 16 + n15;
            atomicAdd(&ws[WS_S + (bb * 2 + 0) * 128 + c], s0p[nt]);
            atomicAdd(&ws[WS_S + (bb * 2 + 1) * 128 + c], s1p[nt]);
        }
    }
    if (hf == 0 && lane == 0) {     // both halves hold identical alpha sums; count once
        atomicAdd(&ws[WS_A + bb * 2 + 0], aA0);
        atomicAdd(&ws[WS_A + bb * 2 + 1], aA1);
    }

    // ---- per-batch completion counter; 16th finisher runs this batch's epilogue
    __syncthreads();
    if (tid == 0) {
        __threadfence();
        int old = atomicAdd((int*)ws + WS_CNT + bb, 1);
        do_epi = (old == BPB - 1) ? 1 : 0;
    }
    __syncthreads();

    if (do_epi) {
        // reuse lds_h1 as float scratch: sS[256], sA[2], pooled[128], part[512]
        float* eb     = (float*)lds_h1;
        float* e_sS   = eb;
        float* e_sA   = eb + 256;
        float* e_pool = eb + 264;
        float* e_part = eb + 392;

        if (tid < 256) e_sS[tid] = atomicAdd(&ws[WS_S + bb * 256 + tid], 0.f);
        if (tid < 2)   e_sA[tid] = atomicAdd(&ws[WS_A + bb * 2 + tid], 0.f);
        __syncthreads();

        const int i = tid & 127, seg = tid >> 7;      // 4-way split-K over 512 thr
        const int h = i >> 6;
        {
            float dot = 0.f;
            #pragma unroll 8
            for (int d0 = 0; d0 < 32; ++d0) {
                const int d = seg * 32 + d0;
                dot += e_sS[h * 128 + d] * Wv[d * 128 + i];
            }
            e_part[tid] = dot;
        }
        __syncthreads();
        if (tid < 128)
            e_pool[i] = (e_part[i] + e_part[128 + i] + e_part[256 + i] + e_part[384 + i]
                         + e_sA[h] * bv[i]) * (1.0f / 4096.0f);
        __syncthreads();

        {
            float o = 0.f;
            #pragma unroll 8
            for (int d0 = 0; d0 < 32; ++d0) {
                const int d = seg * 32 + d0;
                o += e_pool[d] * Wo[d * 128 + i];
            }
            e_part[tid] = o;
        }
        __syncthreads();
        if (tid < 128)
            out[bb * 128 + i] = bo[i] + e_part[i] + e_part[128 + i] + e_part[256 + i] + e_part[384 + i];
    }
}

extern "C" void kernel_launch(void* const* d_in, const int* in_sizes, int n_in,
                              void* d_out, int out_size, void* d_ws, size_t ws_size,
                              hipStream_t stream) {
    const float* u     = (const float*)d_in[0];
    // d_in[1] = x : unused by the reference
    const float* W1    = (const float*)d_in[2];
    const float* b1    = (const float*)d_in[3];
    const float* W2    = (const float*)d_in[4];
    const float* b2    = (const float*)d_in[5];
    const float* embed = (const float*)d_in[6];
    const float* Wq    = (const float*)d_in[7];
    const float* bq    = (const float*)d_in[8];
    const float* Wk    = (const float*)d_in[9];
    const float* bk    = (const float*)d_in[10];
    const float* Wv    = (const float*)d_in[11];
    const float* bv    = (const float*)d_in[12];
    const float* Wo    = (const float*)d_in[13];
    const float* bo    = (const float*)d_in[14];
    float* ws  = (float*)d_ws;
    float* out = (float*)d_out;

    hipLaunchKernelGGL(precompute_kernel, dim3(14), dim3(256), 0, stream,
                       embed, Wq, bq, Wk, bk, W1, W2, ws);
    hipLaunchKernelGGL(mlp_pool_kernel, dim3(GRID_MLP), dim3(512), 0, stream,
                       u, b1, b2, Wv, bv, Wo, bo, ws, out);
}